// Round 2
// baseline (150.234 us; speedup 1.0000x reference)
//
#include <hip/hip_runtime.h>
#include <stdint.h>

// DBMLLoss on MI355X.
// feats: [4096,512] f32 (L2-normalized rows), labels: [4096] i32, out: scalar f32.
//
// sim = F F^T computed twice (pass1 -> row stats, pass2 -> adaptive selection stats)
// with bf16 MFMA (16x16x32). Row-variance terms use the sum-of-squares identity so
// only two passes over sim are needed. Diagonal forced to exactly 1.0f.

#define Bn 4096
#define Dk 512
#define NCHUNK 8          // col chunks; grid = 32 x 8 = 256 blocks
#define CWIDTH 512        // cols per chunk
#define BM 128            // rows per block
#define TBN 128           // cols per tile step
#define BK 64             // K step
#define ONE_EPS 0.99999f  // 1 - 1e-5

typedef short bf16x8 __attribute__((ext_vector_type(8)));
typedef float f32x4 __attribute__((ext_vector_type(4)));

__device__ __forceinline__ unsigned short f2bf(float x) {
  unsigned int u = __float_as_uint(x);
  u += 0x7fffu + ((u >> 16) & 1u);   // RNE
  return (unsigned short)(u >> 16);
}

// featT layout: [kb 0..63][row 0..4095][8 bf16]  (kb = k/8) -> staging reads are
// 16B/lane, consecutive lanes = consecutive rows = contiguous 1KB per wave.
__global__ __launch_bounds__(256) void convert_kernel(const float* __restrict__ feats,
                                                      unsigned short* __restrict__ featT) {
  int g = blockIdx.x * 256 + threadIdx.x;  // 0..262143 ; g = kb*4096 + row
  int row = g & 4095;
  int kb = g >> 12;
  const float* src = feats + (size_t)row * Dk + kb * 8;
  f32x4 f0 = *(const f32x4*)(src);
  f32x4 f1 = *(const f32x4*)(src + 4);
  union { unsigned short u[8]; bf16x8 v; } o;
  o.u[0] = f2bf(f0[0]); o.u[1] = f2bf(f0[1]); o.u[2] = f2bf(f0[2]); o.u[3] = f2bf(f0[3]);
  o.u[4] = f2bf(f1[0]); o.u[5] = f2bf(f1[1]); o.u[6] = f2bf(f1[2]); o.u[7] = f2bf(f1[3]);
  *(bf16x8*)(featT + (size_t)g * 8) = o.v;
}

// PHASE 1 partials (5): sum, sumsq, max_neg, min_pos, pos_cnt
// PHASE 2 partials (6): n_pos, n_neg, sum_sel, sumsq_sel, fp_sum, fn_sum
template <int PHASE>
__global__ __launch_bounds__(512, 2) void phase_kernel(const unsigned short* __restrict__ featT,
                                                       const int* __restrict__ labels,
                                                       const float* __restrict__ rs,
                                                       float* __restrict__ part) {
  // LDS tiles k-outer: [kb 0..7][r 0..127][8 bf16] -> conflict-free ds_read_b128
  __shared__ short As[1024 * 8];
  __shared__ short Bs[1024 * 8];
  __shared__ int rl[BM];
  __shared__ int cl[CWIDTH];

  const int tid = threadIdx.x;
  const int wid = tid >> 6;
  const int lane = tid & 63;
  const int WR = wid & 3;    // 4 row groups of 32
  const int WC = wid >> 2;   // 2 col groups of 64
  const int l15 = lane & 15;
  const int l4 = lane >> 4;
  const int row0 = blockIdx.x * BM;
  const int chunk0 = blockIdx.y * CWIDTH;

  for (int i = tid; i < BM; i += 512) rl[i] = labels[row0 + i];
  for (int i = tid; i < CWIDTH; i += 512) cl[i] = labels[chunk0 + i];
  __syncthreads();

  int rlab[2][4], rowl[2][4];
#pragma unroll
  for (int m = 0; m < 2; ++m)
#pragma unroll
    for (int r = 0; r < 4; ++r) {
      int lr = WR * 32 + m * 16 + l4 * 4 + r;  // tile-local row (C/D: row=(l>>4)*4+reg)
      rowl[m][r] = lr;
      rlab[m][r] = rl[lr];
    }

  float thrp[2][4], thrn[2][4];
  if constexpr (PHASE == 2) {
#pragma unroll
    for (int m = 0; m < 2; ++m)
#pragma unroll
      for (int r = 0; r < 4; ++r) {
        thrp[m][r] = rs[2 * Bn + row0 + rowl[m][r]];  // max_neg
        thrn[m][r] = rs[3 * Bn + row0 + rowl[m][r]];  // min_pos
      }
  }

  float s0[2][4], s1[2][4], s2[2][4], s3[2][4], s4[2][4], s5[2][4];
#pragma unroll
  for (int m = 0; m < 2; ++m)
#pragma unroll
    for (int r = 0; r < 4; ++r) {
      s0[m][r] = 0.f; s1[m][r] = 0.f;
      s2[m][r] = (PHASE == 1) ? -__builtin_inff() : 0.f;
      s3[m][r] = (PHASE == 1) ? __builtin_inff() : 0.f;
      s4[m][r] = 0.f; s5[m][r] = 0.f;
    }

  const int q0 = wid * 64 + lane;

  for (int ct = 0; ct < 4; ++ct) {
    const int col0 = chunk0 + ct * TBN;
    f32x4 acc[2][4];
#pragma unroll
    for (int m = 0; m < 2; ++m)
#pragma unroll
      for (int n = 0; n < 4; ++n) acc[m][n] = (f32x4){0.f, 0.f, 0.f, 0.f};

    for (int kt = 0; kt < Dk / BK; ++kt) {
      bf16x8 ra[2], rb[2];
#pragma unroll
      for (int i = 0; i < 2; ++i) {
        int q = q0 + i * 512;
        int r = q & 127;
        int kb = q >> 7;
        size_t koff = (size_t)(kt * 8 + kb) * Bn * 8;
        ra[i] = *(const bf16x8*)(featT + koff + (size_t)(row0 + r) * 8);
        rb[i] = *(const bf16x8*)(featT + koff + (size_t)(col0 + r) * 8);
      }
      __syncthreads();  // previous step's frag reads done
#pragma unroll
      for (int i = 0; i < 2; ++i) {
        int q = q0 + i * 512;
        *(bf16x8*)&As[q * 8] = ra[i];
        *(bf16x8*)&Bs[q * 8] = rb[i];
      }
      __syncthreads();
#pragma unroll
      for (int ks = 0; ks < 2; ++ks) {
        const int kb = ks * 4 + l4;
        bf16x8 a[2], b[4];
#pragma unroll
        for (int m = 0; m < 2; ++m)
          a[m] = *(const bf16x8*)&As[(kb * 128 + WR * 32 + m * 16 + l15) * 8];
#pragma unroll
        for (int n = 0; n < 4; ++n)
          b[n] = *(const bf16x8*)&Bs[(kb * 128 + WC * 64 + n * 16 + l15) * 8];
#pragma unroll
        for (int m = 0; m < 2; ++m)
#pragma unroll
          for (int n = 0; n < 4; ++n)
            acc[m][n] = __builtin_amdgcn_mfma_f32_16x16x32_bf16(a[m], b[n], acc[m][n], 0, 0, 0);
      }
    }

    // ---- fold this 128x128 tile into per-lane row stats ----
    const bool diag = (col0 == row0);
    int clab[4], lcolt[4];
#pragma unroll
    for (int n = 0; n < 4; ++n) {
      lcolt[n] = WC * 64 + n * 16 + l15;            // tile-local col
      clab[n] = cl[ct * TBN + lcolt[n]];
    }
#pragma unroll
    for (int m = 0; m < 2; ++m)
#pragma unroll
      for (int n = 0; n < 4; ++n)
#pragma unroll
        for (int r = 0; r < 4; ++r) {
          float s = acc[m][n][r];
          if (diag && (lcolt[n] == rowl[m][r])) s = 1.0f;  // exact self-sim
          bool same = (rlab[m][r] == clab[n]);
          if constexpr (PHASE == 1) {
            s0[m][r] += s;
            s1[m][r] += s * s;
            if (!same) s2[m][r] = fmaxf(s2[m][r], s);
            else if (s < ONE_EPS) { s3[m][r] = fminf(s3[m][r], s); s4[m][r] += 1.0f; }
          } else {
            bool psel = same && (s < ONE_EPS) && (s - 0.1f < thrp[m][r]);
            bool nsel = (!same) && (s + 0.1f > thrn[m][r]);
            if (psel) { s0[m][r] += 1.0f; s4[m][r] += __expf(2.0f - 2.0f * s); }
            if (nsel) { s1[m][r] += 1.0f; s5[m][r] += __expf(2.0f * s - 1.2f); }
            if (psel || nsel) { s2[m][r] += s; s3[m][r] += s * s; }
          }
        }
  }

  // butterfly across the 16 lanes holding different cols of the same rows
#pragma unroll
  for (int d = 1; d < 16; d <<= 1) {
#pragma unroll
    for (int m = 0; m < 2; ++m)
#pragma unroll
      for (int r = 0; r < 4; ++r) {
        s0[m][r] += __shfl_xor(s0[m][r], d);
        s1[m][r] += __shfl_xor(s1[m][r], d);
        if constexpr (PHASE == 1) {
          s2[m][r] = fmaxf(s2[m][r], __shfl_xor(s2[m][r], d));
          s3[m][r] = fminf(s3[m][r], __shfl_xor(s3[m][r], d));
          s4[m][r] += __shfl_xor(s4[m][r], d);
        } else {
          s2[m][r] += __shfl_xor(s2[m][r], d);
          s3[m][r] += __shfl_xor(s3[m][r], d);
          s4[m][r] += __shfl_xor(s4[m][r], d);
          s5[m][r] += __shfl_xor(s5[m][r], d);
        }
      }
  }

  if (l15 == 0) {
    const int slot = blockIdx.y * 2 + WC;  // 16 slots per row
#pragma unroll
    for (int m = 0; m < 2; ++m)
#pragma unroll
      for (int r = 0; r < 4; ++r) {
        int rowg = row0 + rowl[m][r];
        part[(size_t)(0 * Bn + rowg) * 16 + slot] = s0[m][r];
        part[(size_t)(1 * Bn + rowg) * 16 + slot] = s1[m][r];
        part[(size_t)(2 * Bn + rowg) * 16 + slot] = s2[m][r];
        part[(size_t)(3 * Bn + rowg) * 16 + slot] = s3[m][r];
        part[(size_t)(4 * Bn + rowg) * 16 + slot] = s4[m][r];
        if constexpr (PHASE == 2)
          part[(size_t)(5 * Bn + rowg) * 16 + slot] = s5[m][r];
      }
  }
}

__global__ __launch_bounds__(256) void reduce1_kernel(const float* __restrict__ part,
                                                      float* __restrict__ rs) {
  int row = blockIdx.x * 256 + threadIdx.x;
  float sum = 0.f, ssq = 0.f, pc = 0.f;
  float mxn = -__builtin_inff(), mnp = __builtin_inff();
#pragma unroll
  for (int sl = 0; sl < 16; ++sl) {
    sum += part[(size_t)(0 * Bn + row) * 16 + sl];
    ssq += part[(size_t)(1 * Bn + row) * 16 + sl];
    mxn = fmaxf(mxn, part[(size_t)(2 * Bn + row) * 16 + sl]);
    mnp = fminf(mnp, part[(size_t)(3 * Bn + row) * 16 + sl]);
    pc += part[(size_t)(4 * Bn + row) * 16 + sl];
  }
  rs[0 * Bn + row] = sum;
  rs[1 * Bn + row] = ssq;
  rs[2 * Bn + row] = mxn;
  rs[3 * Bn + row] = mnp;
  rs[4 * Bn + row] = pc;
}

__global__ __launch_bounds__(256) void finalize_kernel(const float* __restrict__ p2,
                                                       const float* __restrict__ rs,
                                                       float* __restrict__ out) {
  int tid = threadIdx.x;
  int row = blockIdx.x * 256 + tid;
  float np = 0.f, nn = 0.f, ssel = 0.f, qsel = 0.f, fp = 0.f, fn = 0.f;
#pragma unroll
  for (int sl = 0; sl < 16; ++sl) {
    np += p2[(size_t)(0 * Bn + row) * 16 + sl];
    nn += p2[(size_t)(1 * Bn + row) * 16 + sl];
    ssel += p2[(size_t)(2 * Bn + row) * 16 + sl];
    qsel += p2[(size_t)(3 * Bn + row) * 16 + sl];
    fp += p2[(size_t)(4 * Bn + row) * 16 + sl];
    fn += p2[(size_t)(5 * Bn + row) * 16 + sl];
  }
  float sumall = rs[0 * Bn + row];
  float ssqall = rs[1 * Bn + row];
  float pc = rs[4 * Bn + row];

  float mean_all = sumall * (1.0f / Bn);
  float sigma_all = ssqall - (float)Bn * mean_all * mean_all;
  float cnt = fmaxf(np + nn, 1.0f);
  float mean_sel = ssel / cnt;
  float sigma_sel = qsel / cnt - mean_sel * mean_sel;
  float loss = __logf(1.0f + fp) + __logf(1.0f + fn) +
               0.5f * (fabsf(mean_all - mean_sel) + fabsf(sigma_all - sigma_sel));
  bool valid = (pc > 0.5f) && (pc < (float)(Bn - 1) - 0.5f) && (np > 0.5f) && (nn > 0.5f);
  float v = valid ? loss : 0.f;
#pragma unroll
  for (int d = 1; d < 64; d <<= 1) v += __shfl_xor(v, d);
  __shared__ float ls[4];
  if ((tid & 63) == 0) ls[tid >> 6] = v;
  __syncthreads();
  if (tid == 0) atomicAdd(out, (ls[0] + ls[1] + ls[2] + ls[3]) * (1.0f / (float)Bn));
}

extern "C" void kernel_launch(void* const* d_in, const int* in_sizes, int n_in,
                              void* d_out, int out_size, void* d_ws, size_t ws_size,
                              hipStream_t stream) {
  const float* feats = (const float*)d_in[0];
  const int* labels = (const int*)d_in[1];
  float* out = (float*)d_out;
  char* ws = (char*)d_ws;

  // ws layout (bytes):
  unsigned short* featT = (unsigned short*)(ws);              // 4,194,304
  float* p1 = (float*)(ws + 4194304);                         // 5*4096*16*4 = 1,310,720
  float* rs = (float*)(ws + 4194304 + 1310720);               // 5*4096*4   =    81,920
  float* p2 = (float*)(ws + 4194304 + 1310720 + 81920);       // 6*4096*16*4= 1,572,864

  hipMemsetAsync(d_out, 0, sizeof(float), stream);
  convert_kernel<<<1024, 256, 0, stream>>>(feats, featT);
  dim3 g(Bn / BM, NCHUNK);
  phase_kernel<1><<<g, 512, 0, stream>>>(featT, labels, nullptr, p1);
  reduce1_kernel<<<Bn / 256, 256, 0, stream>>>(p1, rs);
  phase_kernel<2><<<g, 512, 0, stream>>>(featT, labels, rs, p2);
  finalize_kernel<<<Bn / 256, 256, 0, stream>>>(p2, rs, out);
}